// Round 11
// baseline (155.231 us; speedup 1.0000x reference)
//
#include <hip/hip_runtime.h>

typedef _Float16 half8 __attribute__((ext_vector_type(8)));
typedef _Float16 half2_t __attribute__((ext_vector_type(2)));
typedef __fp16 fp16x2 __attribute__((ext_vector_type(2)));
typedef float f32x4 __attribute__((ext_vector_type(4)));

#define MFMA16(a, b, c) __builtin_amdgcn_mfma_f32_16x16x32_f16((a), (b), (c), 0, 0, 0)

__device__ __forceinline__ float exp2_fast(float x) {
#if __has_builtin(__builtin_amdgcn_exp2f)
    return __builtin_amdgcn_exp2f(x);
#else
    return exp2f(x);
#endif
}

// tanh(x) = (e-1)/(e+1), e = 2^(2*log2(e)*x).
__device__ __forceinline__ float tanh_fast(float x) {
    x = fminf(x, 22.f);
    float e = exp2_fast(2.885390082f * x);
    return (e - 1.f) * __builtin_amdgcn_rcpf(e + 1.f);
}

__device__ __forceinline__ float dot2f(unsigned a, unsigned b, float c) {
#if __has_builtin(__builtin_amdgcn_fdot2)
    return __builtin_amdgcn_fdot2(__builtin_bit_cast(half2_t, a),
                                  __builtin_bit_cast(half2_t, b), c, false);
#else
    float d;
    asm("v_dot2_f32_f16 %0, %1, %2, %3" : "=v"(d) : "v"(a), "v"(b), "v"(c));
    return d;
#endif
}

// pack 2 relu'd f32 -> 2 fp16 in one dword (v_cvt_pkrtz_f16_f32)
__device__ __forceinline__ unsigned pk_relu(float a, float b) {
    fp16x2 h = __builtin_amdgcn_cvt_pkrtz(fmaxf(a, 0.f), fmaxf(b, 0.f));
    return __builtin_bit_cast(unsigned, h);
}
__device__ __forceinline__ unsigned pk2(float a, float b) {
    fp16x2 h = __builtin_amdgcn_cvt_pkrtz(a, b);
    return __builtin_bit_cast(unsigned, h);
}

// ---------------------------------------------------------------------------
// K-permuted layout: every inter-layer buffer with N cols stores value of
// original col c at position P_N(c) = (c&15)*(N/16) + (c>>4). MFMA D-frag
// (col=lane&15, row=(lane>>4)*4+reg) then writes N/16 CONTIGUOUS halves per
// (lane,reg) -> vector ds_write. Weight images are pre-permuted in K to match.
//
// Workspace (bytes):
//   0        enc_img: e_w1[128][72] natural @0h, e_w3[32][72] P4 @9216h,
//                     r1_wih[32][32] P2 (rows>=20 zero) @11520h
//   25600    w2img:   e_w2[64][128] P8
//   41984    dec_img: d_w1[64][32] P2 @0h, d_w2[128][72] P4 @2048h
//   65536    dw3img:  d_w3[64][128] P8
//   81920    xp1  fp16 131072 x 32 (P2 cols; only P2(u<20) meaningful)
//   10567680 dbuf fp16 131072 x 32 (P2 cols)
//   18956288 rnn_img  u32 64 x 32 (natural; dw26 = f32 bias)
//   18964480 dump     fp16 (garbage sink for rnn lanes >= 32)
// ---------------------------------------------------------------------------

__global__ __launch_bounds__(256) void prep_kernel(
    const float* __restrict__ e_w1, const float* __restrict__ e_w3,
    const float* __restrict__ r1_wih, const float* __restrict__ e_w2,
    const float* __restrict__ d_w1, const float* __restrict__ d_w2,
    const float* __restrict__ d_w3,
    const float* __restrict__ r1_whh, const float* __restrict__ r2_wih,
    const float* __restrict__ r2_whh,
    const float* __restrict__ r2_bih, const float* __restrict__ r2_bhh,
    _Float16* __restrict__ enc_img, _Float16* __restrict__ w2img,
    _Float16* __restrict__ dec_img, _Float16* __restrict__ dw3img,
    unsigned* __restrict__ rnn_img)
{
    int i = blockIdx.x * 256 + threadIdx.x;
    if (i < 8192) {                          // e_w1 (128,64) natural K
        int r = i >> 6, c = i & 63;
        enc_img[r * 72 + c] = (_Float16)e_w1[i];
    } else if (i < 10240) {                  // e_w3 (32,64) K perm P4
        int j = i - 8192; int r = j >> 6, c = j & 63;
        enc_img[9216 + r * 72 + ((c & 15) * 4 + (c >> 4))] = (_Float16)e_w3[j];
    } else if (i < 11264) {                  // r1_wih (20,32)->[32][32] P2, pad 0
        int j = i - 10240; int r = j >> 5, k = j & 31;
        float v = (r < 20) ? r1_wih[r * 32 + k] : 0.f;
        enc_img[11520 + r * 32 + ((k & 15) * 2 + (k >> 4))] = (_Float16)v;
    } else if (i < 19456) {                  // e_w2 (64,128) P8
        int j = i - 11264; int r = j >> 7, c = j & 127;
        w2img[r * 128 + ((c & 15) * 8 + (c >> 4))] = (_Float16)e_w2[j];
    } else if (i < 21504) {                  // d_w1 (64,32) P2
        int j = i - 19456; int r = j >> 5, k = j & 31;
        dec_img[r * 32 + ((k & 15) * 2 + (k >> 4))] = (_Float16)d_w1[j];
    } else if (i < 29696) {                  // d_w2 (128,64) P4
        int j = i - 21504; int r = j >> 6, c = j & 63;
        dec_img[2048 + r * 72 + ((c & 15) * 4 + (c >> 4))] = (_Float16)d_w2[j];
    } else if (i < 37888) {                  // d_w3 (64,128) P8
        int j = i - 29696; int r = j >> 7, c = j & 127;
        dw3img[r * 128 + ((c & 15) * 8 + (c >> 4))] = (_Float16)d_w3[j];
    } else if (i < 39936) {                  // rnn_img (natural)
        int j = i - 37888;
        int row = j >> 5, c = j & 31;
        unsigned val = 0;
        if (c == 26) {
            float b = (row < 32) ? (r2_bih[row] + r2_bhh[row]) : 0.f;
            val = __builtin_bit_cast(unsigned, b);
        } else {
            float v0 = 0.f, v1 = 0.f;
            if (row < 32) {
                if (c < 10)      { v0 = r2_wih[row * 20 + 2*c]; v1 = r2_wih[row * 20 + 2*c + 1]; }
                else if (c < 26) { int k = c - 10;
                                   v0 = r2_whh[row * 32 + 2*k]; v1 = r2_whh[row * 32 + 2*k + 1]; }
            } else if (row < 52) {
                int uu = row - 32;
                if (c < 10)      { v0 = r1_whh[uu * 20 + 2*c]; v1 = r1_whh[uu * 20 + 2*c + 1]; }
            }
            unsigned lo = (unsigned)__builtin_bit_cast(unsigned short, (_Float16)v0);
            unsigned hi = (unsigned)__builtin_bit_cast(unsigned short, (_Float16)v1);
            val = lo | (hi << 16);
        }
        rnn_img[j] = val;
    }
}

// ---------------------------------------------------------------------------
// Encoder: x -> relu MLP 64->128->64->32 -> xp1(fp16, P2) ; bias in MFMA C-init,
// vectorized pk epilogues, barrier-free (per-wave 16-row LDS bands).
// ---------------------------------------------------------------------------
__global__ __launch_bounds__(256) void enc_kernel(
    const float* __restrict__ x,
    const float* __restrict__ eb1, const float* __restrict__ eb2,
    const float* __restrict__ eb3,
    const float* __restrict__ r1bih, const float* __restrict__ r1bhh,
    const _Float16* __restrict__ enc_img, const _Float16* __restrict__ w2img,
    unsigned* __restrict__ xp1u)
{
    __shared__ _Float16 a1buf[64 * 136];
    __shared__ _Float16 a2buf[64 * 72];
    __shared__ _Float16 a3buf[64 * 40];

    const int tid  = threadIdx.x;
    const int lane = tid & 63;
    const int wv   = tid >> 6;
    const int l15  = lane & 15;
    const int kg   = lane >> 4;
    const int rowA  = blockIdx.x * 64 + wv * 16 + l15;
    const int rowDl = wv * 16 + kg * 4;
    const int rowDg = blockIdx.x * 64 + rowDl;

    // ---- L1: 64 -> 128
    half8 a0, a1f;
    {
        const float* xr = x + (size_t)rowA * 64 + kg * 8;
        f32x4 p0 = *(const f32x4*)(xr);
        f32x4 p1 = *(const f32x4*)(xr + 4);
        f32x4 p2 = *(const f32x4*)(xr + 32);
        f32x4 p3 = *(const f32x4*)(xr + 36);
        #pragma unroll
        for (int j = 0; j < 4; ++j) {
            a0[j]    = (_Float16)p0[j];
            a0[j+4]  = (_Float16)p1[j];
            a1f[j]   = (_Float16)p2[j];
            a1f[j+4] = (_Float16)p3[j];
        }
    }
    f32x4 acc1[8];
    #pragma unroll
    for (int ct = 0; ct < 8; ++ct) {
        float b = eb1[ct * 16 + l15];
        acc1[ct] = (f32x4){b, b, b, b};
    }
    #pragma unroll
    for (int ct = 0; ct < 8; ++ct) {
        const _Float16* wp = enc_img + (ct * 16 + l15) * 72 + kg * 8;
        half8 b0 = *(const half8*)(wp);
        half8 b1 = *(const half8*)(wp + 32);
        acc1[ct] = MFMA16(a0, b0, acc1[ct]);
        acc1[ct] = MFMA16(a1f, b1, acc1[ct]);
    }
    #pragma unroll
    for (int r = 0; r < 4; ++r) {
        uint4 v;
        v.x = pk_relu(acc1[0][r], acc1[1][r]);
        v.y = pk_relu(acc1[2][r], acc1[3][r]);
        v.z = pk_relu(acc1[4][r], acc1[5][r]);
        v.w = pk_relu(acc1[6][r], acc1[7][r]);
        *(uint4*)(a1buf + (rowDl + r) * 136 + l15 * 8) = v;
    }

    // ---- L2: 128 -> 64
    half8 af[4];
    #pragma unroll
    for (int kt = 0; kt < 4; ++kt)
        af[kt] = *(const half8*)(a1buf + (wv * 16 + l15) * 136 + kt * 32 + kg * 8);
    f32x4 acc2[4];
    #pragma unroll
    for (int ct = 0; ct < 4; ++ct) {
        float b = eb2[ct * 16 + l15];
        acc2[ct] = (f32x4){b, b, b, b};
    }
    #pragma unroll
    for (int ct = 0; ct < 4; ++ct) {
        const _Float16* wp = w2img + (ct * 16 + l15) * 128 + kg * 8;
        #pragma unroll
        for (int kt = 0; kt < 4; ++kt) {
            half8 b = *(const half8*)(wp + kt * 32);
            acc2[ct] = MFMA16(af[kt], b, acc2[ct]);
        }
    }
    #pragma unroll
    for (int r = 0; r < 4; ++r) {
        uint2 v;
        v.x = pk_relu(acc2[0][r], acc2[1][r]);
        v.y = pk_relu(acc2[2][r], acc2[3][r]);
        *(uint2*)(a2buf + (rowDl + r) * 72 + l15 * 4) = v;
    }

    // ---- L3: 64 -> 32
    half8 c0 = *(const half8*)(a2buf + (wv * 16 + l15) * 72 + kg * 8);
    half8 c1 = *(const half8*)(a2buf + (wv * 16 + l15) * 72 + 32 + kg * 8);
    f32x4 acc3[2];
    #pragma unroll
    for (int ct = 0; ct < 2; ++ct) {
        float b = eb3[ct * 16 + l15];
        acc3[ct] = (f32x4){b, b, b, b};
    }
    #pragma unroll
    for (int ct = 0; ct < 2; ++ct) {
        const _Float16* wp = enc_img + 9216 + (ct * 16 + l15) * 72 + kg * 8;
        half8 b0 = *(const half8*)(wp);
        half8 b1 = *(const half8*)(wp + 32);
        acc3[ct] = MFMA16(c0, b0, acc3[ct]);
        acc3[ct] = MFMA16(c1, b1, acc3[ct]);
    }
    #pragma unroll
    for (int r = 0; r < 4; ++r)
        *(unsigned*)(a3buf + (rowDl + r) * 40 + l15 * 2) =
            pk_relu(acc3[0][r], acc3[1][r]);

    // ---- L4: 32 -> 20 (projection; cols >= 20 are garbage, never read)
    half8 d0 = *(const half8*)(a3buf + (wv * 16 + l15) * 40 + kg * 8);
    f32x4 acc4[2];
    {
        int c1i = 16 + l15; if (c1i > 19) c1i = 19;
        float b0v = r1bih[l15] + r1bhh[l15];
        float b1v = r1bih[c1i] + r1bhh[c1i];
        acc4[0] = (f32x4){b0v, b0v, b0v, b0v};
        acc4[1] = (f32x4){b1v, b1v, b1v, b1v};
    }
    #pragma unroll
    for (int ct = 0; ct < 2; ++ct) {
        const _Float16* wp = enc_img + 11520 + (ct * 16 + l15) * 32 + kg * 8;
        half8 b0 = *(const half8*)(wp);
        acc4[ct] = MFMA16(d0, b0, acc4[ct]);
    }
    #pragma unroll
    for (int r = 0; r < 4; ++r)
        xp1u[(size_t)(rowDg + r) * 16 + l15] = pk2(acc4[0][r], acc4[1][r]);
}

// ---------------------------------------------------------------------------
// Fused RNN1 + RNN2 + ReLU (round-6 proven structure, 432 cyc/iter floor).
// xp1 now fp16 P2-permuted (col P2(u)); dbuf written P2-permuted.
// ---------------------------------------------------------------------------
__global__ __launch_bounds__(64) void rnn_kernel(
    const _Float16* __restrict__ xph,
    const unsigned* __restrict__ rnn_img,
    _Float16* __restrict__ dbuf)
{
    const int lane  = threadIdx.x & 63;
    const int batch = blockIdx.x;

    unsigned w[26];
    float base_b;
    {
        const unsigned* wr = rnn_img + lane * 32;
        #pragma unroll
        for (int i = 0; i < 6; ++i) {
            uint4 q = *(const uint4*)(wr + i * 4);
            w[i*4+0] = q.x; w[i*4+1] = q.y; w[i*4+2] = q.z; w[i*4+3] = q.w;
        }
        uint4 q = *(const uint4*)(wr + 24);
        w[24] = q.x; w[25] = q.y;
        base_b = __builtin_bit_cast(float, q.z);
    }

    const bool isB = lane < 32;
    int ua = lane - 32;
    if (ua < 0 || ua > 19) ua = 0;
    const _Float16* xcol = xph + (size_t)batch * 32 + ((ua & 15) * 2 + (ua >> 4));

    const int up = ((lane & 31) & 15) * 2 + ((lane & 31) >> 4);   // P2(u)
    const size_t DUMP_ELEMS = 4198400;
    _Float16* dst = isB ? (dbuf + (size_t)batch * 32 + up)
                        : (dbuf + DUMP_ELEMS + (size_t)batch * 64 + lane);
    const size_t dstride = isB ? 8192 : 0;

    const unsigned sel = (lane & 1) ? 0x01000504u : 0x05040100u;
    unsigned hs[26];

    // prologue: h1(0) = tanh(x(0)) on lanes>=32; h2(-1) = 0 on lanes<32
    {
        float x0 = (float)xcol[0];
        float h0 = isB ? 0.f : tanh_fast(x0);
        _Float16 h16 = (_Float16)h0;
        unsigned own  = (unsigned)__builtin_bit_cast(unsigned short, h16);
        unsigned dppv = (unsigned)__builtin_amdgcn_update_dpp(0, (int)own, 0xB1, 0xF, 0xF, false);
        unsigned pk   = __builtin_amdgcn_perm(dppv, own, sel);
        #pragma unroll
        for (int i = 0; i < 10; ++i)
            hs[i]    = (unsigned)__builtin_amdgcn_ds_bpermute((32 + 2*i) * 4, (int)pk);
        #pragma unroll
        for (int i = 0; i < 16; ++i)
            hs[10+i] = (unsigned)__builtin_amdgcn_ds_bpermute((2*i) * 4, (int)pk);
    }

    // x prefetch ring (row stride 256*32 = 8192 halves)
    float xr[8];
    #pragma unroll
    for (int j = 0; j < 8; ++j)
        xr[j] = (float)xcol[(size_t)(1 + j) * 8192];

    #pragma unroll 1
    for (int t0 = 0; t0 < 512; t0 += 8) {
        #pragma unroll
        for (int j = 0; j < 8; ++j) {
            const int t = t0 + j;
            float a0 = isB ? base_b : xr[j];
            float a1 = 0.f, a2 = 0.f, a3 = 0.f, a4 = 0.f, a5 = 0.f, a6 = 0.f, a7 = 0.f;
            a0 = dot2f(w[0],  hs[0],  a0);
            a1 = dot2f(w[1],  hs[1],  a1);
            a2 = dot2f(w[2],  hs[2],  a2);
            a3 = dot2f(w[3],  hs[3],  a3);
            a4 = dot2f(w[4],  hs[4],  a4);
            a5 = dot2f(w[5],  hs[5],  a5);
            a6 = dot2f(w[6],  hs[6],  a6);
            a7 = dot2f(w[7],  hs[7],  a7);
            a0 = dot2f(w[8],  hs[8],  a0);
            a1 = dot2f(w[9],  hs[9],  a1);
            a2 = dot2f(w[10], hs[10], a2);
            a3 = dot2f(w[11], hs[11], a3);
            a4 = dot2f(w[12], hs[12], a4);
            a5 = dot2f(w[13], hs[13], a5);
            a6 = dot2f(w[14], hs[14], a6);
            a7 = dot2f(w[15], hs[15], a7);
            a0 = dot2f(w[16], hs[16], a0);
            a1 = dot2f(w[17], hs[17], a1);
            a2 = dot2f(w[18], hs[18], a2);
            a3 = dot2f(w[19], hs[19], a3);
            a4 = dot2f(w[20], hs[20], a4);
            a5 = dot2f(w[21], hs[21], a5);
            a6 = dot2f(w[22], hs[22], a6);
            a7 = dot2f(w[23], hs[23], a7);
            a0 = dot2f(w[24], hs[24], a0);
            a1 = dot2f(w[25], hs[25], a1);
            float r = ((a0 + a1) + (a2 + a3)) + ((a4 + a5) + (a6 + a7));
            float h = tanh_fast(r);
            _Float16 h16 = (_Float16)h;

            _Float16 z = (_Float16)0.f;
            *dst = (h16 > z) ? h16 : z;
            dst += dstride;

            unsigned own  = (unsigned)__builtin_bit_cast(unsigned short, h16);
            unsigned dppv = (unsigned)__builtin_amdgcn_update_dpp(0, (int)own, 0xB1, 0xF, 0xF, false);
            unsigned pk   = __builtin_amdgcn_perm(dppv, own, sel);
            #pragma unroll
            for (int i = 0; i < 10; ++i)
                hs[i]    = (unsigned)__builtin_amdgcn_ds_bpermute((32 + 2*i) * 4, (int)pk);
            #pragma unroll
            for (int i = 0; i < 16; ++i)
                hs[10+i] = (unsigned)__builtin_amdgcn_ds_bpermute((2*i) * 4, (int)pk);

            xr[j] = (float)xcol[(size_t)(t + 9) * 8192];
        }
    }
}

// ---------------------------------------------------------------------------
// Decoder: dbuf(fp16 P2) -> relu 32->64 -> relu 64->128 -> 128->64 -> out f32
// ---------------------------------------------------------------------------
__global__ __launch_bounds__(256) void dec_kernel(
    const _Float16* __restrict__ dbuf,
    const float* __restrict__ db1, const float* __restrict__ db2,
    const float* __restrict__ db3,
    const _Float16* __restrict__ dec_img, const _Float16* __restrict__ dw3img,
    float* __restrict__ out)
{
    __shared__ _Float16 a1buf[64 * 72];
    __shared__ _Float16 a2buf[64 * 136];

    const int tid  = threadIdx.x;
    const int lane = tid & 63;
    const int wv   = tid >> 6;
    const int l15  = lane & 15;
    const int kg   = lane >> 4;
    const int rowA  = blockIdx.x * 64 + wv * 16 + l15;
    const int rowDl = wv * 16 + kg * 4;
    const int rowDg = blockIdx.x * 64 + rowDl;

    // ---- L1: 32 -> 64
    half8 a0 = *(const half8*)(dbuf + (size_t)rowA * 32 + kg * 8);
    f32x4 acc1[4];
    #pragma unroll
    for (int ct = 0; ct < 4; ++ct) {
        float b = db1[ct * 16 + l15];
        acc1[ct] = (f32x4){b, b, b, b};
    }
    #pragma unroll
    for (int ct = 0; ct < 4; ++ct) {
        half8 b = *(const half8*)(dec_img + (ct * 16 + l15) * 32 + kg * 8);
        acc1[ct] = MFMA16(a0, b, acc1[ct]);
    }
    #pragma unroll
    for (int r = 0; r < 4; ++r) {
        uint2 v;
        v.x = pk_relu(acc1[0][r], acc1[1][r]);
        v.y = pk_relu(acc1[2][r], acc1[3][r]);
        *(uint2*)(a1buf + (rowDl + r) * 72 + l15 * 4) = v;
    }

    // ---- L2: 64 -> 128
    half8 af0 = *(const half8*)(a1buf + (wv * 16 + l15) * 72 + kg * 8);
    half8 af1 = *(const half8*)(a1buf + (wv * 16 + l15) * 72 + 32 + kg * 8);
    f32x4 acc2[8];
    #pragma unroll
    for (int ct = 0; ct < 8; ++ct) {
        float b = db2[ct * 16 + l15];
        acc2[ct] = (f32x4){b, b, b, b};
    }
    #pragma unroll
    for (int ct = 0; ct < 8; ++ct) {
        const _Float16* wp = dec_img + 2048 + (ct * 16 + l15) * 72 + kg * 8;
        half8 b0 = *(const half8*)(wp);
        half8 b1 = *(const half8*)(wp + 32);
        acc2[ct] = MFMA16(af0, b0, acc2[ct]);
        acc2[ct] = MFMA16(af1, b1, acc2[ct]);
    }
    #pragma unroll
    for (int r = 0; r < 4; ++r) {
        uint4 v;
        v.x = pk_relu(acc2[0][r], acc2[1][r]);
        v.y = pk_relu(acc2[2][r], acc2[3][r]);
        v.z = pk_relu(acc2[4][r], acc2[5][r]);
        v.w = pk_relu(acc2[6][r], acc2[7][r]);
        *(uint4*)(a2buf + (rowDl + r) * 136 + l15 * 8) = v;
    }

    // ---- L3: 128 -> 64 (natural output order, no relu)
    half8 cf[4];
    #pragma unroll
    for (int kt = 0; kt < 4; ++kt)
        cf[kt] = *(const half8*)(a2buf + (wv * 16 + l15) * 136 + kt * 32 + kg * 8);
    f32x4 acc3[4];
    #pragma unroll
    for (int ct = 0; ct < 4; ++ct) {
        float b = db3[ct * 16 + l15];
        acc3[ct] = (f32x4){b, b, b, b};
    }
    #pragma unroll
    for (int ct = 0; ct < 4; ++ct) {
        const _Float16* wp = dw3img + (ct * 16 + l15) * 128 + kg * 8;
        #pragma unroll
        for (int kt = 0; kt < 4; ++kt) {
            half8 b = *(const half8*)(wp + kt * 32);
            acc3[ct] = MFMA16(cf[kt], b, acc3[ct]);
        }
    }
    #pragma unroll
    for (int ct = 0; ct < 4; ++ct) {
        int col = ct * 16 + l15;
        #pragma unroll
        for (int r = 0; r < 4; ++r)
            out[(size_t)(rowDg + r) * 64 + col] = acc3[ct][r];
    }
}

// ---------------------------------------------------------------------------
extern "C" void kernel_launch(void* const* d_in, const int* in_sizes, int n_in,
                              void* d_out, int out_size, void* d_ws, size_t ws_size,
                              hipStream_t stream) {
    const float* x      = (const float*)d_in[0];
    const float* e_w1   = (const float*)d_in[1];
    const float* e_b1   = (const float*)d_in[2];
    const float* e_w2   = (const float*)d_in[3];
    const float* e_b2   = (const float*)d_in[4];
    const float* e_w3   = (const float*)d_in[5];
    const float* e_b3   = (const float*)d_in[6];
    const float* r1_wih = (const float*)d_in[7];
    const float* r1_whh = (const float*)d_in[8];
    const float* r1_bih = (const float*)d_in[9];
    const float* r1_bhh = (const float*)d_in[10];
    const float* r2_wih = (const float*)d_in[11];
    const float* r2_whh = (const float*)d_in[12];
    const float* r2_bih = (const float*)d_in[13];
    const float* r2_bhh = (const float*)d_in[14];
    const float* d_w1   = (const float*)d_in[15];
    const float* d_b1   = (const float*)d_in[16];
    const float* d_w2   = (const float*)d_in[17];
    const float* d_b2   = (const float*)d_in[18];
    const float* d_w3   = (const float*)d_in[19];
    const float* d_b3   = (const float*)d_in[20];

    char* ws = (char*)d_ws;
    _Float16* enc_img = (_Float16*)(ws + 0);
    _Float16* w2img   = (_Float16*)(ws + 25600);
    _Float16* dec_img = (_Float16*)(ws + 41984);
    _Float16* dw3img  = (_Float16*)(ws + 65536);
    unsigned* xp1u    = (unsigned*)(ws + 81920);
    _Float16* xph     = (_Float16*)(ws + 81920);
    _Float16* dbuf    = (_Float16*)(ws + 10567680);
    unsigned* rnn_img = (unsigned*)(ws + 18956288);

    prep_kernel<<<156, 256, 0, stream>>>(e_w1, e_w3, r1_wih, e_w2, d_w1, d_w2, d_w3,
                                         r1_whh, r2_wih, r2_whh, r2_bih, r2_bhh,
                                         enc_img, w2img, dec_img, dw3img, rnn_img);
    enc_kernel<<<2048, 256, 0, stream>>>(x, e_b1, e_b2, e_b3, r1_bih, r1_bhh,
                                         enc_img, w2img, xp1u);
    rnn_kernel<<<256, 64, 0, stream>>>(xph, rnn_img, dbuf);
    dec_kernel<<<2048, 256, 0, stream>>>(dbuf, d_b1, d_b2, d_b3, dec_img, dw3img,
                                         (float*)d_out);
}

// Round 14
// 151.976 us; speedup vs baseline: 1.0214x; 1.0214x over previous
//
#include <hip/hip_runtime.h>

typedef _Float16 half8 __attribute__((ext_vector_type(8)));
typedef _Float16 half2_t __attribute__((ext_vector_type(2)));
typedef float f32x4 __attribute__((ext_vector_type(4)));

#define MFMA16(a, b, c) __builtin_amdgcn_mfma_f32_16x16x32_f16((a), (b), (c), 0, 0, 0)

__device__ __forceinline__ float exp2_fast(float x) {
#if __has_builtin(__builtin_amdgcn_exp2f)
    return __builtin_amdgcn_exp2f(x);
#else
    return exp2f(x);
#endif
}

// tanh(x) = (e-1)/(e+1), e = 2^(2*log2(e)*x). Single clamp guards f32 overflow;
// negative side underflows to 0 -> returns -1 correctly. fminf(NaN,22)=22.
__device__ __forceinline__ float tanh_fast(float x) {
    x = fminf(x, 22.f);
    float e = exp2_fast(2.885390082f * x);
    return (e - 1.f) * __builtin_amdgcn_rcpf(e + 1.f);
}

// d = a.x*b.x + a.y*b.y + c  (fp16 inputs, fp32 accumulate)
__device__ __forceinline__ float dot2f(unsigned a, unsigned b, float c) {
#if __has_builtin(__builtin_amdgcn_fdot2)
    return __builtin_amdgcn_fdot2(__builtin_bit_cast(half2_t, a),
                                  __builtin_bit_cast(half2_t, b), c, false);
#else
    float d;
    asm("v_dot2_f32_f16 %0, %1, %2, %3" : "=v"(d) : "v"(a), "v"(b), "v"(c));
    return d;
#endif
}

// ---------------------------------------------------------------------------
// Workspace layout (bytes):
//   0        enc_img   (fp16): W1[128][72] @0h, W3[32][72] @9216h, r1_wih[32][40] @11520h
//   25600    w2enc_img (fp16): e_w2 [64][128]
//   41984    dec_img   (fp16): d_w1[64][40] @0h, d_w2[128][72] @2560h
//   65536    dw3_img   (fp16): d_w3 [64][128]
//   81920    xp1  f32  131072 x 20
//   10567680 dbuf fp16 131072 x 32   (ends 18956288)
//   18956288 rnn_img   u32: 64 rows x 32 dwords
//            row<32   : dw0-9 = W2ih pairs, dw10-25 = W2hh pairs, dw26 = f32 bias
//            32<=row<52: dw0-9 = W1hh pairs, rest 0
//   18964480 dump      fp16: 256 x 64  (garbage sink for lanes >= 32)
// ---------------------------------------------------------------------------

__global__ __launch_bounds__(256) void prep_kernel(
    const float* __restrict__ e_w1, const float* __restrict__ e_w3,
    const float* __restrict__ r1_wih, const float* __restrict__ e_w2,
    const float* __restrict__ d_w1, const float* __restrict__ d_w2,
    const float* __restrict__ d_w3,
    const float* __restrict__ r1_whh, const float* __restrict__ r2_wih,
    const float* __restrict__ r2_whh,
    const float* __restrict__ r2_bih, const float* __restrict__ r2_bhh,
    _Float16* __restrict__ enc_img, _Float16* __restrict__ w2img,
    _Float16* __restrict__ dec_img, _Float16* __restrict__ dw3img,
    unsigned* __restrict__ rnn_img)
{
    int i = blockIdx.x * 256 + threadIdx.x;
    if (i < 8192) {                         // e_w1 (128,64) -> [128][72]
        int r = i >> 6, c = i & 63;
        enc_img[r * 72 + c] = (_Float16)e_w1[i];
    } else if (i < 10240) {                 // e_w3 (32,64) -> @9216 [32][72]
        int j = i - 8192; int r = j >> 6, c = j & 63;
        enc_img[9216 + r * 72 + c] = (_Float16)e_w3[j];
    } else if (i < 10880) {                 // r1_wih (20,32) -> @11520 [32][40]
        int j = i - 10240; int r = j >> 5, c = j & 31;
        enc_img[11520 + r * 40 + c] = (_Float16)r1_wih[j];
    } else if (i < 19072) {                 // e_w2 (64,128)
        int j = i - 10880;
        w2img[j] = (_Float16)e_w2[j];
    } else if (i < 21120) {                 // d_w1 (64,32) -> [64][40]
        int j = i - 19072; int r = j >> 5, c = j & 31;
        dec_img[r * 40 + c] = (_Float16)d_w1[j];
    } else if (i < 29312) {                 // d_w2 (128,64) -> @2560 [128][72]
        int j = i - 21120; int r = j >> 6, c = j & 63;
        dec_img[2560 + r * 72 + c] = (_Float16)d_w2[j];
    } else if (i < 37504) {                 // d_w3 (64,128)
        int j = i - 29312;
        dw3img[j] = (_Float16)d_w3[j];
    } else if (i < 39552) {                 // rnn_img: 64 x 32 dwords
        int j = i - 37504;
        int row = j >> 5, c = j & 31;
        unsigned val = 0;
        if (c == 26) {
            float b = (row < 32) ? (r2_bih[row] + r2_bhh[row]) : 0.f;
            val = __builtin_bit_cast(unsigned, b);
        } else {
            float v0 = 0.f, v1 = 0.f;
            if (row < 32) {
                if (c < 10)      { v0 = r2_wih[row * 20 + 2*c]; v1 = r2_wih[row * 20 + 2*c + 1]; }
                else if (c < 26) { int k = c - 10;
                                   v0 = r2_whh[row * 32 + 2*k]; v1 = r2_whh[row * 32 + 2*k + 1]; }
            } else if (row < 52) {
                int uu = row - 32;
                if (c < 10)      { v0 = r1_whh[uu * 20 + 2*c]; v1 = r1_whh[uu * 20 + 2*c + 1]; }
            }
            unsigned lo = (unsigned)__builtin_bit_cast(unsigned short, (_Float16)v0);
            unsigned hi = (unsigned)__builtin_bit_cast(unsigned short, (_Float16)v1);
            val = lo | (hi << 16);
        }
        rnn_img[j] = val;
    }
}

// ---------------------------------------------------------------------------
// Encoder: x(131072,64) -> relu MLP 64->128->64->32 -> xp1 = h3 @ r1_wih^T + b
// Barrier-free: weights read directly from global (L1/L2-resident images);
// all LDS activation traffic stays inside the owning wave's 16-row band
// (writes: wv*16+kg*4+r, reads: wv*16+l15), single-wave DS is in-order.
// ---------------------------------------------------------------------------
__global__ __launch_bounds__(256) void enc_kernel(
    const float* __restrict__ x,
    const float* __restrict__ eb1, const float* __restrict__ eb2,
    const float* __restrict__ eb3,
    const float* __restrict__ r1bih, const float* __restrict__ r1bhh,
    const _Float16* __restrict__ enc_img, const _Float16* __restrict__ w2img,
    float* __restrict__ xp1)
{
    __shared__ _Float16 a1buf[64 * 136];
    __shared__ _Float16 a2buf[64 * 72];
    __shared__ _Float16 a3buf[64 * 40];

    const int tid  = threadIdx.x;
    const int lane = tid & 63;
    const int wv   = tid >> 6;
    const int l15  = lane & 15;
    const int kg   = lane >> 4;
    const int rowA  = blockIdx.x * 64 + wv * 16 + l15;
    const int rowDl = wv * 16 + kg * 4;
    const int rowDg = blockIdx.x * 64 + rowDl;

    // ---- L1: 64 -> 128  (A from global fp32 x; B from enc_img global)
    half8 a0, a1f;
    {
        const float* xr = x + (size_t)rowA * 64 + kg * 8;
        f32x4 p0 = *(const f32x4*)(xr);
        f32x4 p1 = *(const f32x4*)(xr + 4);
        f32x4 p2 = *(const f32x4*)(xr + 32);
        f32x4 p3 = *(const f32x4*)(xr + 36);
        #pragma unroll
        for (int j = 0; j < 4; ++j) {
            a0[j]    = (_Float16)p0[j];
            a0[j+4]  = (_Float16)p1[j];
            a1f[j]   = (_Float16)p2[j];
            a1f[j+4] = (_Float16)p3[j];
        }
    }
    f32x4 acc1[8] = {};
    #pragma unroll
    for (int ct = 0; ct < 8; ++ct) {
        const _Float16* wp = enc_img + (ct * 16 + l15) * 72 + kg * 8;
        half8 b0 = *(const half8*)(wp);
        half8 b1 = *(const half8*)(wp + 32);
        acc1[ct] = MFMA16(a0, b0, acc1[ct]);
        acc1[ct] = MFMA16(a1f, b1, acc1[ct]);
    }
    #pragma unroll
    for (int ct = 0; ct < 8; ++ct) {
        int col = ct * 16 + l15;
        float b = eb1[col];
        #pragma unroll
        for (int r = 0; r < 4; ++r) {
            float v = fmaxf(acc1[ct][r] + b, 0.f);
            a1buf[(rowDl + r) * 136 + col] = (_Float16)v;
        }
    }

    // ---- L2: 128 -> 64
    half8 af[4];
    #pragma unroll
    for (int kt = 0; kt < 4; ++kt)
        af[kt] = *(const half8*)(a1buf + (wv * 16 + l15) * 136 + kt * 32 + kg * 8);
    f32x4 acc2[4] = {};
    #pragma unroll
    for (int ct = 0; ct < 4; ++ct) {
        const _Float16* wp = w2img + (ct * 16 + l15) * 128 + kg * 8;
        #pragma unroll
        for (int kt = 0; kt < 4; ++kt) {
            half8 b = *(const half8*)(wp + kt * 32);
            acc2[ct] = MFMA16(af[kt], b, acc2[ct]);
        }
    }
    #pragma unroll
    for (int ct = 0; ct < 4; ++ct) {
        int col = ct * 16 + l15;
        float b = eb2[col];
        #pragma unroll
        for (int r = 0; r < 4; ++r) {
            float v = fmaxf(acc2[ct][r] + b, 0.f);
            a2buf[(rowDl + r) * 72 + col] = (_Float16)v;
        }
    }

    // ---- L3: 64 -> 32
    half8 c0 = *(const half8*)(a2buf + (wv * 16 + l15) * 72 + kg * 8);
    half8 c1 = *(const half8*)(a2buf + (wv * 16 + l15) * 72 + 32 + kg * 8);
    f32x4 acc3[2] = {};
    #pragma unroll
    for (int ct = 0; ct < 2; ++ct) {
        const _Float16* wp = enc_img + 9216 + (ct * 16 + l15) * 72 + kg * 8;
        half8 b0 = *(const half8*)(wp);
        half8 b1 = *(const half8*)(wp + 32);
        acc3[ct] = MFMA16(c0, b0, acc3[ct]);
        acc3[ct] = MFMA16(c1, b1, acc3[ct]);
    }
    #pragma unroll
    for (int ct = 0; ct < 2; ++ct) {
        int col = ct * 16 + l15;
        float b = eb3[col];
        #pragma unroll
        for (int r = 0; r < 4; ++r) {
            float v = fmaxf(acc3[ct][r] + b, 0.f);
            a3buf[(rowDl + r) * 40 + col] = (_Float16)v;
        }
    }

    // ---- L4: 32 -> 20 (rnn1 input projection)
    half8 d0 = *(const half8*)(a3buf + (wv * 16 + l15) * 40 + kg * 8);
    f32x4 acc4[2] = {};
    #pragma unroll
    for (int ct = 0; ct < 2; ++ct) {
        const _Float16* wp = enc_img + 11520 + (ct * 16 + l15) * 40 + kg * 8;
        half8 b0 = *(const half8*)(wp);
        acc4[ct] = MFMA16(d0, b0, acc4[ct]);
    }
    #pragma unroll
    for (int ct = 0; ct < 2; ++ct) {
        int col = ct * 16 + l15;
        if (col < 20) {
            float bs = r1bih[col] + r1bhh[col];
            #pragma unroll
            for (int r = 0; r < 4; ++r)
                xp1[(size_t)(rowDg + r) * 20 + col] = acc4[ct][r] + bs;
        }
    }
}

// ---------------------------------------------------------------------------
// Fused RNN1 + RNN2 + ReLU. 1 batch chain per wave, grid = 256 blocks.
// (Proven structure: 432 cyc/iter is this recurrence's latency floor —
// rounds 4/6/7/8 all plateau 430-470 across four broadcast/ILP structures;
// the MFMA-based form (rounds 12/13) carries an unresolved layout bug.)
// Divergence-free inner loop; broadcast via ds_bpermute_b32:
//   lanes 0-31:  h2(t)   = tanh(bias + W2ih.h1(t) + W2hh.h2(t-1))  -> store
//   lanes 32-51: h1(t+1) = tanh(x(t+1) + W1hh.h1(t))               -> dump store
//   lanes 52-63: zero weights, dump store (harmless)
// ---------------------------------------------------------------------------
__global__ __launch_bounds__(64) void rnn_kernel(
    const float* __restrict__ xp1,
    const unsigned* __restrict__ rnn_img,
    _Float16* __restrict__ dbuf)
{
    const int lane  = threadIdx.x & 63;
    const int batch = blockIdx.x;

    // per-lane weight row: 26 packed fp16 pairs + f32 bias in dword 26
    unsigned w[26];
    float base_b;
    {
        const unsigned* wr = rnn_img + lane * 32;
        #pragma unroll
        for (int i = 0; i < 6; ++i) {
            uint4 q = *(const uint4*)(wr + i * 4);
            w[i*4+0] = q.x; w[i*4+1] = q.y; w[i*4+2] = q.z; w[i*4+3] = q.w;
        }
        uint4 q = *(const uint4*)(wr + 24);
        w[24] = q.x; w[25] = q.y;
        base_b = __builtin_bit_cast(float, q.z);
    }

    const bool isB = lane < 32;
    int ua = lane - 32;
    if (ua < 0 || ua > 19) ua = 0;
    const float* xcol = xp1 + (size_t)batch * 20 + ua;

    // store target: real rows for lanes<32, dump region otherwise (stride 0)
    const size_t DUMP_ELEMS = 4198400;   // (18964480 - 10567680) / 2
    _Float16* dst = isB ? (dbuf + (size_t)batch * 32 + lane)
                        : (dbuf + DUMP_ELEMS + (size_t)batch * 64 + lane);
    const size_t dstride = isB ? 8192 : 0;

    const unsigned sel = (lane & 1) ? 0x01000504u : 0x05040100u;
    unsigned hs[26];

    // prologue: h1(0) = tanh(x(0)) on lanes>=32; h2(-1) = 0 on lanes<32
    {
        float x0 = xcol[0];
        float h0 = isB ? 0.f : tanh_fast(x0);
        _Float16 h16 = (_Float16)h0;
        unsigned own  = (unsigned)__builtin_bit_cast(unsigned short, h16);
        unsigned dppv = (unsigned)__builtin_amdgcn_update_dpp(0, (int)own, 0xB1, 0xF, 0xF, false);
        unsigned pk   = __builtin_amdgcn_perm(dppv, own, sel);
        #pragma unroll
        for (int i = 0; i < 10; ++i)
            hs[i]    = (unsigned)__builtin_amdgcn_ds_bpermute((32 + 2*i) * 4, (int)pk);
        #pragma unroll
        for (int i = 0; i < 16; ++i)
            hs[10+i] = (unsigned)__builtin_amdgcn_ds_bpermute((2*i) * 4, (int)pk);
    }

    // x prefetch ring: xr[j] = x(t+1) for t = t0+j   (row stride 256*20 = 5120)
    float xr[8];
    #pragma unroll
    for (int j = 0; j < 8; ++j)
        xr[j] = xcol[(size_t)(1 + j) * 5120];

    #pragma unroll 1
    for (int t0 = 0; t0 < 512; t0 += 8) {
        #pragma unroll
        for (int j = 0; j < 8; ++j) {
            const int t = t0 + j;
            // 8 accumulators, chain depth 4
            float a0 = isB ? base_b : xr[j];
            float a1 = 0.f, a2 = 0.f, a3 = 0.f, a4 = 0.f, a5 = 0.f, a6 = 0.f, a7 = 0.f;
            a0 = dot2f(w[0],  hs[0],  a0);
            a1 = dot2f(w[1],  hs[1],  a1);
            a2 = dot2f(w[2],  hs[2],  a2);
            a3 = dot2f(w[3],  hs[3],  a3);
            a4 = dot2f(w[4],  hs[4],  a4);
            a5 = dot2f(w[5],  hs[5],  a5);
            a6 = dot2f(w[6],  hs[6],  a6);
            a7 = dot2f(w[7],  hs[7],  a7);
            a0 = dot2f(w[8],  hs[8],  a0);
            a1 = dot2f(w[9],  hs[9],  a1);
            a2 = dot2f(w[10], hs[10], a2);
            a3 = dot2f(w[11], hs[11], a3);
            a4 = dot2f(w[12], hs[12], a4);
            a5 = dot2f(w[13], hs[13], a5);
            a6 = dot2f(w[14], hs[14], a6);
            a7 = dot2f(w[15], hs[15], a7);
            a0 = dot2f(w[16], hs[16], a0);
            a1 = dot2f(w[17], hs[17], a1);
            a2 = dot2f(w[18], hs[18], a2);
            a3 = dot2f(w[19], hs[19], a3);
            a4 = dot2f(w[20], hs[20], a4);
            a5 = dot2f(w[21], hs[21], a5);
            a6 = dot2f(w[22], hs[22], a6);
            a7 = dot2f(w[23], hs[23], a7);
            a0 = dot2f(w[24], hs[24], a0);
            a1 = dot2f(w[25], hs[25], a1);
            float r = ((a0 + a1) + (a2 + a3)) + ((a4 + a5) + (a6 + a7));
            float h = tanh_fast(r);
            _Float16 h16 = (_Float16)h;

            // unconditional store (real rows for lanes<32, dump otherwise)
            _Float16 z = (_Float16)0.f;
            *dst = (h16 > z) ? h16 : z;
            dst += dstride;

            // pack pairs in even lanes, then crossbar-broadcast 26 dwords
            unsigned own  = (unsigned)__builtin_bit_cast(unsigned short, h16);
            unsigned dppv = (unsigned)__builtin_amdgcn_update_dpp(0, (int)own, 0xB1, 0xF, 0xF, false);
            unsigned pk   = __builtin_amdgcn_perm(dppv, own, sel);
            #pragma unroll
            for (int i = 0; i < 10; ++i)
                hs[i]    = (unsigned)__builtin_amdgcn_ds_bpermute((32 + 2*i) * 4, (int)pk);
            #pragma unroll
            for (int i = 0; i < 16; ++i)
                hs[10+i] = (unsigned)__builtin_amdgcn_ds_bpermute((2*i) * 4, (int)pk);

            // refill ring (unguarded; tail over-read stays inside d_ws and
            // only feeds the never-consumed h1(512))
            xr[j] = xcol[(size_t)(t + 9) * 5120];
        }
    }
}

// ---------------------------------------------------------------------------
// Decoder MLP: dbuf(131072,32 fp16) -> relu 32->64 -> relu 64->128 -> 128->64
// Barrier-free, weights direct from global (see enc_kernel note).
// ---------------------------------------------------------------------------
__global__ __launch_bounds__(256) void dec_kernel(
    const _Float16* __restrict__ dbuf,
    const float* __restrict__ db1, const float* __restrict__ db2,
    const float* __restrict__ db3,
    const _Float16* __restrict__ dec_img, const _Float16* __restrict__ dw3img,
    float* __restrict__ out)
{
    __shared__ _Float16 a1buf[64 * 72];
    __shared__ _Float16 a2buf[64 * 136];

    const int tid  = threadIdx.x;
    const int lane = tid & 63;
    const int wv   = tid >> 6;
    const int l15  = lane & 15;
    const int kg   = lane >> 4;
    const int rowA  = blockIdx.x * 64 + wv * 16 + l15;
    const int rowDl = wv * 16 + kg * 4;
    const int rowDg = blockIdx.x * 64 + rowDl;

    // ---- L1: 32 -> 64
    half8 a0 = *(const half8*)(dbuf + (size_t)rowA * 32 + kg * 8);
    f32x4 acc1[4] = {};
    #pragma unroll
    for (int ct = 0; ct < 4; ++ct) {
        half8 b = *(const half8*)(dec_img + (ct * 16 + l15) * 40 + kg * 8);
        acc1[ct] = MFMA16(a0, b, acc1[ct]);
    }
    #pragma unroll
    for (int ct = 0; ct < 4; ++ct) {
        int col = ct * 16 + l15;
        float b = db1[col];
        #pragma unroll
        for (int r = 0; r < 4; ++r) {
            float v = fmaxf(acc1[ct][r] + b, 0.f);
            a1buf[(rowDl + r) * 72 + col] = (_Float16)v;
        }
    }

    // ---- L2: 64 -> 128
    half8 af0 = *(const half8*)(a1buf + (wv * 16 + l15) * 72 + kg * 8);
    half8 af1 = *(const half8*)(a1buf + (wv * 16 + l15) * 72 + 32 + kg * 8);
    f32x4 acc2[8] = {};
    #pragma unroll
    for (int ct = 0; ct < 8; ++ct) {
        const _Float16* wp = dec_img + 2560 + (ct * 16 + l15) * 72 + kg * 8;
        half8 b0 = *(const half8*)(wp);
        half8 b1 = *(const half8*)(wp + 32);
        acc2[ct] = MFMA16(af0, b0, acc2[ct]);
        acc2[ct] = MFMA16(af1, b1, acc2[ct]);
    }
    #pragma unroll
    for (int ct = 0; ct < 8; ++ct) {
        int col = ct * 16 + l15;
        float b = db2[col];
        #pragma unroll
        for (int r = 0; r < 4; ++r) {
            float v = fmaxf(acc2[ct][r] + b, 0.f);
            a2buf[(rowDl + r) * 136 + col] = (_Float16)v;
        }
    }

    // ---- L3: 128 -> 64, no relu
    half8 cf[4];
    #pragma unroll
    for (int kt = 0; kt < 4; ++kt)
        cf[kt] = *(const half8*)(a2buf + (wv * 16 + l15) * 136 + kt * 32 + kg * 8);
    f32x4 acc3[4] = {};
    #pragma unroll
    for (int ct = 0; ct < 4; ++ct) {
        const _Float16* wp = dw3img + (ct * 16 + l15) * 128 + kg * 8;
        #pragma unroll
        for (int kt = 0; kt < 4; ++kt) {
            half8 b = *(const half8*)(wp + kt * 32);
            acc3[ct] = MFMA16(cf[kt], b, acc3[ct]);
        }
    }
    #pragma unroll
    for (int ct = 0; ct < 4; ++ct) {
        int col = ct * 16 + l15;
        float b = db3[col];
        #pragma unroll
        for (int r = 0; r < 4; ++r)
            out[(size_t)(rowDg + r) * 64 + col] = acc3[ct][r] + b;
    }
}

// ---------------------------------------------------------------------------
extern "C" void kernel_launch(void* const* d_in, const int* in_sizes, int n_in,
                              void* d_out, int out_size, void* d_ws, size_t ws_size,
                              hipStream_t stream) {
    const float* x      = (const float*)d_in[0];
    const float* e_w1   = (const float*)d_in[1];
    const float* e_b1   = (const float*)d_in[2];
    const float* e_w2   = (const float*)d_in[3];
    const float* e_b2   = (const float*)d_in[4];
    const float* e_w3   = (const float*)d_in[5];
    const float* e_b3   = (const float*)d_in[6];
    const float* r1_wih = (const float*)d_in[7];
    const float* r1_whh = (const float*)d_in[8];
    const float* r1_bih = (const float*)d_in[9];
    const float* r1_bhh = (const float*)d_in[10];
    const float* r2_wih = (const float*)d_in[11];
    const float* r2_whh = (const float*)d_in[12];
    const float* r2_bih = (const float*)d_in[13];
    const float* r2_bhh = (const float*)d_in[14];
    const float* d_w1   = (const float*)d_in[15];
    const float* d_b1   = (const float*)d_in[16];
    const float* d_w2   = (const float*)d_in[17];
    const float* d_b2   = (const float*)d_in[18];
    const float* d_w3   = (const float*)d_in[19];
    const float* d_b3   = (const float*)d_in[20];

    char* ws = (char*)d_ws;
    _Float16* enc_img = (_Float16*)(ws + 0);
    _Float16* w2img   = (_Float16*)(ws + 25600);
    _Float16* dec_img = (_Float16*)(ws + 41984);
    _Float16* dw3img  = (_Float16*)(ws + 65536);
    float*    xp1     = (float*)(ws + 81920);
    _Float16* dbuf    = (_Float16*)(ws + 10567680);
    unsigned* rnn_img = (unsigned*)(ws + 18956288);

    prep_kernel<<<155, 256, 0, stream>>>(e_w1, e_w3, r1_wih, e_w2, d_w1, d_w2, d_w3,
                                         r1_whh, r2_wih, r2_whh, r2_bih, r2_bhh,
                                         enc_img, w2img, dec_img, dw3img, rnn_img);
    enc_kernel<<<2048, 256, 0, stream>>>(x, e_b1, e_b2, e_b3, r1_bih, r1_bhh,
                                         enc_img, w2img, xp1);
    rnn_kernel<<<256, 64, 0, stream>>>(xp1, rnn_img, dbuf);
    dec_kernel<<<2048, 256, 0, stream>>>(dbuf, d_b1, d_b2, d_b3, dec_img, dw3img,
                                         (float*)d_out);
}